// Round 9
// baseline (457.255 us; speedup 1.0000x reference)
//
#include <hip/hip_runtime.h>
#include <hip/hip_bf16.h>

// LocalResnetPointnet v9: v8 + coalesced-write gather (LDS bin-tile transpose)
// + fold kernels eliminated (in-kernel epilogue bias, overlapped with MFMA).

#define G_ALL 131072   // B*T
#define HD    128
#define NBINS 16384

typedef __attribute__((ext_vector_type(8))) short short8;
typedef __attribute__((ext_vector_type(4))) float f32x4;

#define MFMA16(a, b, c) __builtin_amdgcn_mfma_f32_16x16x32_bf16(a, b, c, 0, 0, 0)

__device__ __forceinline__ float bf16_to_f32(unsigned short u) {
  union { unsigned int u; float f; } v; v.u = ((unsigned int)u) << 16; return v.f;
}
__device__ __forceinline__ unsigned short f32_to_bf16(float f) {
  union { float f; unsigned int u; } v; v.f = f;
  unsigned int u = v.u;
  u += 0x7fffu + ((u >> 16) & 1u);   // RNE (no NaNs in this workload)
  return (unsigned short)(u >> 16);
}
// order-preserving float -> uint key for atomicMax
__device__ __forceinline__ unsigned int f32_key(float f) {
  union { float f; unsigned int u; } v; v.f = f;
  return (v.u & 0x80000000u) ? ~v.u : (v.u | 0x80000000u);
}
__device__ __forceinline__ float key_f32(unsigned int k) {
  union { unsigned int u; float f; } v;
  v.u = (k & 0x80000000u) ? (k & 0x7fffffffu) : ~k;
  return v.f;
}
__device__ __forceinline__ int bin_of(float p0, float p2) {
  float x = p0 / 1.101f + 0.5f;
  x = fminf(fmaxf(x, 0.0f), 1.0f - 1e-6f);
  int xi = (int)(x * 128.0f);
  float z = p2 / 1.101f + 0.5f;
  z = fminf(fmaxf(z, 0.0f), 1.0f - 1e-6f);
  int zi = (int)(z * 128.0f);
  return xi + 128 * zi;
}
__device__ __forceinline__ short8 relu8(short8 a) {
  short8 r;
#pragma unroll
  for (int e = 0; e < 8; e++) r[e] = a[e] < 0 ? (short)0 : a[e];
  return r;
}

// ---------------- prep: Sp = fcw@ws0, bsp = fcb@ws0, zero pools+hist -------
__global__ void prep_kernel(const float* __restrict__ fcw,
                            const float* __restrict__ fcb,
                            const float* __restrict__ ws0,
                            float* __restrict__ Sp, float* __restrict__ bsp,
                            unsigned int* __restrict__ pool,
                            int* __restrict__ hist) {
  int j = threadIdx.x;  // 128 threads
  for (int d = 0; d < 3; d++) {
    float s = 0.f;
    for (int ch = 0; ch < 256; ch++)
      s = fmaf(fcw[d * 256 + ch], ws0[ch * HD + j], s);
    Sp[d * HD + j] = s;
  }
  float s = 0.f;
  for (int ch = 0; ch < 256; ch++)
    s = fmaf(fcb[ch], ws0[ch * HD + j], s);
  bsp[j] = s;
  for (int k = j; k < 4 * 2 * 128; k += 128) pool[k] = 0u;
  for (int k = j; k < 2 * NBINS; k += 128) hist[k] = 0;
}

// ---------------- weight transform: transpose + bf16 cast ------------------
__global__ void wprep_kernel(const float* __restrict__ w0,
                             const float* __restrict__ w1,
                             const float* __restrict__ ws,
                             unsigned short* __restrict__ B0t,
                             unsigned short* __restrict__ W0t,
                             unsigned short* __restrict__ W1t,
                             unsigned short* __restrict__ WSt) {
  int gid = blockIdx.x * 256 + threadIdx.x;
  float v;
  unsigned short* dstp;
  int dst;
  if (gid < 32768) {                       // B0t: [n][k] from w0[0] (256x128)
    int n = gid >> 8, k = gid & 255;
    v = w0[k * 128 + n];
    dstp = B0t; dst = gid;
  } else if (gid < 98304) {                // W0t stages 1..4, rows 0..127
    int i = gid - 32768; int s = i >> 14; int n = (i >> 7) & 127; int k = i & 127;
    v = w0[(size_t)((s + 1) * 256 + k) * 128 + n];
    dstp = W0t; dst = i;
  } else if (gid < 180224) {               // W1t stages 0..4
    int i = gid - 98304; int s = i >> 14; int n = (i >> 7) & 127; int k = i & 127;
    v = w1[(size_t)(s * 128 + k) * 128 + n];
    dstp = W1t; dst = i;
  } else if (gid < 245760) {               // WSt stages 1..4, rows 0..127
    int i = gid - 180224; int s = i >> 14; int n = (i >> 7) & 127; int k = i & 127;
    v = ws[(size_t)((s + 1) * 256 + k) * 128 + n];
    dstp = WSt; dst = i;
  } else return;
  dstp[dst] = f32_to_bf16(v);
}

// ---------------- scatter pipeline -----------------------------------------
__global__ __launch_bounds__(256) void index_kernel(const float* __restrict__ p,
                                                    int* __restrict__ hist) {
  int g = blockIdx.x * 256 + threadIdx.x;
  int b = g >> 16;
  int idx = bin_of(p[3 * (size_t)g], p[3 * (size_t)g + 2]);
  atomicAdd(&hist[b * NBINS + idx], 1);
}

__global__ __launch_bounds__(1024) void scan_kernel(int* __restrict__ hist,
                                                    int* __restrict__ offsets) {
  __shared__ int sd[1024];
  int t = threadIdx.x;
  int vals[32];
  int s = 0;
#pragma unroll
  for (int i = 0; i < 32; i++) { vals[i] = hist[t * 32 + i]; s += vals[i]; }
  sd[t] = s;
  __syncthreads();
  for (int d = 1; d < 1024; d <<= 1) {
    int v = (t >= d) ? sd[t - d] : 0;
    __syncthreads();
    sd[t] += v;
    __syncthreads();
  }
  int run = sd[t] - s;  // exclusive prefix
#pragma unroll
  for (int i = 0; i < 32; i++) {
    offsets[t * 32 + i] = run;
    hist[t * 32 + i] = run;  // cursor copy (in-place)
    run += vals[i];
  }
  if (t == 1023) offsets[32768] = run;  // sentinel = G_ALL
}

__global__ __launch_bounds__(256) void fill_kernel(const float* __restrict__ p,
                                                   int* __restrict__ cursor,
                                                   int* __restrict__ order) {
  int g = blockIdx.x * 256 + threadIdx.x;
  int b = g >> 16;
  int idx = bin_of(p[3 * (size_t)g], p[3 * (size_t)g + 2]);
  int pos = atomicAdd(&cursor[b * NBINS + idx], 1);
  order[pos] = g;
}

// gather + mean: block = 64 bins; register accumulate -> LDS transpose ->
// fully-coalesced 256 B output stores (lane = bin).
__global__ __launch_bounds__(256) void gather_kernel(
    const unsigned short* __restrict__ c, const int* __restrict__ offsets,
    const int* __restrict__ order, float* __restrict__ out) {
  __shared__ float acc[129 * 65];  // [ch 0..127 | cnt row 128][bin 0..63]
  const int tid = threadIdx.x;
  const int wave = tid >> 6, lane = tid & 63;
  const int B0 = blockIdx.x * 64;          // global bin base (0..32767)
  const int b = B0 >> 14;

  for (int i = tid; i < 129 * 65; i += 256) acc[i] = 0.f;
  __syncthreads();

  for (int bi = 0; bi < 16; bi++) {
    const int binL = wave * 16 + bi;
    const int B = B0 + binL;
    const int st = offsets[B], en = offsets[B + 1];
    float a0 = 0.f, a1 = 0.f;
    for (int k = st; k < en; k++) {
      int g = order[k];
      unsigned int u = *(const unsigned int*)(c + (size_t)g * HD + lane * 2);
      a0 += bf16_to_f32((unsigned short)(u & 0xffffu));
      a1 += bf16_to_f32((unsigned short)(u >> 16));
    }
    acc[(2 * lane) * 65 + binL] = a0;
    acc[(2 * lane + 1) * 65 + binL] = a1;
    if (lane == 0) acc[128 * 65 + binL] = (float)(en - st);
  }
  __syncthreads();

  const size_t outBase = (size_t)b * HD * NBINS + (size_t)(B0 & (NBINS - 1));
  const float cnt = fmaxf(acc[128 * 65 + lane], 1.0f);
#pragma unroll
  for (int c2 = 0; c2 < 32; c2++) {
    int ch = wave * 32 + c2;
    out[outBase + (size_t)ch * NBINS + lane] = acc[ch * 65 + lane] / cnt;
  }
}

// ---------------- stage 0: fc_pos + block0 (weight-stationary MFMA) --------
// 8 waves; wave = nt (16 output ch). 512 blocks x 4 tiles of 64 rows.
__global__ __launch_bounds__(512, 4) void stage0_kernel(
    const float* __restrict__ p, const float* __restrict__ fcw,
    const float* __restrict__ fcb,
    const unsigned short* __restrict__ B0t,
    const unsigned short* __restrict__ W1t,
    const float* __restrict__ b0, const float* __restrict__ b1,
    const float* __restrict__ Sp, const float* __restrict__ bsp,
    unsigned short* __restrict__ hout, unsigned int* __restrict__ pool) {
  __shared__ float fcL[1024];                // fcw (768) + fcb (256)
  __shared__ float ptL[64 * 5];              // stride 5: conflict-free q-reads
  __shared__ unsigned short x0t[64 * 264];   // K=256 relu tile; reused as out tile
  __shared__ unsigned short m2[64 * 136];
  const int tid = threadIdx.x;
  const int lane = tid & 63;
  const int q = lane >> 4, l15 = lane & 15;
  const int nt = tid >> 6;                   // wave id = output-ch tile
  const int b = blockIdx.x >> 8;
  const int wrow = nt * 16 + l15;

  // weights -> registers (once per kernel): 8 + 4 short8 = 48 VGPRs
  short8 b0w[8], w1w[4];
#pragma unroll
  for (int kc = 0; kc < 8; kc++)
    b0w[kc] = *(const short8*)(B0t + (size_t)wrow * 256 + kc * 32 + q * 8);
#pragma unroll
  for (int kc = 0; kc < 4; kc++)
    w1w[kc] = *(const short8*)(W1t + (size_t)wrow * 128 + kc * 32 + q * 8);
  const float bias1 = b0[wrow];
  const float bias2 = bsp[wrow] + b1[wrow];
  const float sp0 = Sp[wrow], sp1 = Sp[128 + wrow], sp2 = Sp[256 + wrow];

  for (int k = tid; k < 1024; k += 512)
    fcL[k] = (k < 768) ? fcw[k] : fcb[k - 768];

  for (int it = 0; it < 4; it++) {
    const int rowBase = (blockIdx.x * 4 + it) * 64;
    __syncthreads();  // fcL ready (it0) / prev out-store complete
    if (tid < 192) ptL[(tid / 3) * 5 + (tid % 3)] = p[(size_t)rowBase * 3 + tid];
    // fc_pos: row = tid>>3; channels strided by 8 (bank-conflict-free fcL reads)
    {
      int row = tid >> 3, c8 = tid & 7;
      const float* pr = p + (size_t)(rowBase + row) * 3;
      float p0 = pr[0], p1 = pr[1], p2 = pr[2];
#pragma unroll
      for (int cc = 0; cc < 32; cc++) {
        int ch = c8 + cc * 8;
        float x = fcL[768 + ch] + p0 * fcL[ch] + p1 * fcL[256 + ch] + p2 * fcL[512 + ch];
        x0t[row * 264 + ch] = f32_to_bf16(fmaxf(x, 0.f));
      }
    }
    __syncthreads();  // x0t + ptL ready
    // phase 1: net = relu(x0) @ W0[0] + b0[0]  (K=256)
    f32x4 C1[4];
#pragma unroll
    for (int s = 0; s < 4; s++) C1[s] = (f32x4){bias1, bias1, bias1, bias1};
#pragma unroll
    for (int kc = 0; kc < 8; kc++) {
#pragma unroll
      for (int s = 0; s < 4; s++) {
        short8 Ar = *(const short8*)(&x0t[(s * 16 + l15) * 264 + kc * 32 + q * 8]);
        C1[s] = MFMA16(Ar, b0w[kc], C1[s]);
      }
    }
#pragma unroll
    for (int s = 0; s < 4; s++)
#pragma unroll
      for (int r = 0; r < 4; r++)
        m2[(s * 16 + q * 4 + r) * 136 + nt * 16 + l15] =
            f32_to_bf16(fmaxf(C1[s][r], 0.f));
    __syncthreads();  // m2 ready; x0t phase-1 reads done -> reuse as out tile
    // phase 2: h = m2 @ W1[0] + (p @ Sp + bsp + b1[0])
    f32x4 C2[4];
#pragma unroll
    for (int s = 0; s < 4; s++)
#pragma unroll
      for (int r = 0; r < 4; r++) {
        int row = s * 16 + q * 4 + r;
        C2[s][r] = bias2 + ptL[row * 5] * sp0 + ptL[row * 5 + 1] * sp1 +
                   ptL[row * 5 + 2] * sp2;
      }
#pragma unroll
    for (int kc = 0; kc < 4; kc++) {
#pragma unroll
      for (int s = 0; s < 4; s++) {
        short8 Am = *(const short8*)(&m2[(s * 16 + l15) * 136 + kc * 32 + q * 8]);
        C2[s] = MFMA16(Am, w1w[kc], C2[s]);
      }
    }
#pragma unroll
    for (int s = 0; s < 4; s++)
#pragma unroll
      for (int r = 0; r < 4; r++)
        x0t[(s * 16 + q * 4 + r) * 136 + nt * 16 + l15] = f32_to_bf16(C2[s][r]);
    {
      float m = -1e30f;
#pragma unroll
      for (int s = 0; s < 4; s++)
#pragma unroll
        for (int r = 0; r < 4; r++) m = fmaxf(m, C2[s][r]);
      m = fmaxf(m, __shfl_xor(m, 16, 64));
      m = fmaxf(m, __shfl_xor(m, 32, 64));
      if (lane < 16) atomicMax(&pool[b * 128 + nt * 16 + lane], f32_key(m));
    }
    __syncthreads();  // out tile ready
    {
      int r = tid >> 3, cs = (tid & 7) * 16;
      short8 v0 = *(const short8*)(&x0t[r * 136 + cs]);
      short8 v1 = *(const short8*)(&x0t[r * 136 + cs + 8]);
      *(short8*)(hout + (size_t)(rowBase + r) * 128 + cs) = v0;
      *(short8*)(hout + (size_t)(rowBase + r) * 128 + cs + 8) = v1;
    }
  }
}

// ---------------- stages 1..4 (weight-stationary, in-kernel bias fold) -----
// 8 waves; wave = nt. 512 blocks x 4 tiles of 64 rows. WS fused in phase 1.
// Biases (incl. pooled-half fold) computed per-lane, added in epilogue.
__global__ __launch_bounds__(512, 4) void stageN_kernel(
    const unsigned short* __restrict__ hin, unsigned short* __restrict__ hout,
    const unsigned short* __restrict__ W0t,
    const unsigned short* __restrict__ W1t,
    const unsigned short* __restrict__ WSt,
    const unsigned int* __restrict__ poolPrev,  // [2][128]
    const float* __restrict__ b0s, const float* __restrict__ b1s,
    const float* __restrict__ w0hi,  // f32 rows 128..255 of w0[s]
    const float* __restrict__ wshi,  // f32 rows 128..255 of ws[s]
    unsigned int* __restrict__ pool, int doPool) {
  __shared__ unsigned short At[64 * 136];   // H tile
  __shared__ unsigned short m2[64 * 136];   // relu(net); reused as out tile
  const int tid = threadIdx.x;
  const int lane = tid & 63;
  const int q = lane >> 4, l15 = lane & 15;
  const int nt = tid >> 6;
  const int b = blockIdx.x >> 8;
  const int wrow = nt * 16 + l15;

  // 12 short8 = 48 VGPRs of weights
  short8 w0w[4], w1w[4], wsw[4];
#pragma unroll
  for (int kc = 0; kc < 4; kc++) {
    w0w[kc] = *(const short8*)(W0t + (size_t)wrow * 128 + kc * 32 + q * 8);
    w1w[kc] = *(const short8*)(W1t + (size_t)wrow * 128 + kc * 32 + q * 8);
    wsw[kc] = *(const short8*)(WSt + (size_t)wrow * 128 + kc * 32 + q * 8);
  }
  // in-kernel fold: bias1 = b0 + relu(pool)@w0hi, bias2 = b1 + pool@wshi
  // (overlaps with main-loop MFMAs since it is consumed only in epilogues)
  float bias1 = b0s[wrow], bias2 = b1s[wrow];
  for (int ch = 0; ch < 128; ch++) {
    float pv = key_f32(poolPrev[b * 128 + ch]);
    bias1 = fmaf(fmaxf(pv, 0.f), w0hi[ch * HD + wrow], bias1);
    bias2 = fmaf(pv, wshi[ch * HD + wrow], bias2);
  }
  const int r8 = tid >> 3, cs8 = (tid & 7) * 16;

  for (int it = 0; it < 4; it++) {
    const int rowBase = (blockIdx.x * 4 + it) * 64;
    __syncthreads();  // prev store + prev At reads complete
    {
      const size_t gb = ((size_t)rowBase + r8) * 128 + cs8;
      short8 v0 = *(const short8*)(hin + gb);
      short8 v1 = *(const short8*)(hin + gb + 8);
      *(short8*)(&At[r8 * 136 + cs8]) = v0;
      *(short8*)(&At[r8 * 136 + cs8 + 8]) = v1;
    }
    __syncthreads();  // At ready
    // phase 1: C1 = relu(H)@W0 ; C2 = H@WS (biases deferred)
    f32x4 C1[4], C2[4];
#pragma unroll
    for (int s = 0; s < 4; s++) {
      C1[s] = (f32x4){0.f, 0.f, 0.f, 0.f};
      C2[s] = (f32x4){0.f, 0.f, 0.f, 0.f};
    }
#pragma unroll
    for (int kc = 0; kc < 4; kc++) {
#pragma unroll
      for (int s = 0; s < 4; s++) {
        short8 Ah = *(const short8*)(&At[(s * 16 + l15) * 136 + kc * 32 + q * 8]);
        short8 Ar = relu8(Ah);
        C1[s] = MFMA16(Ar, w0w[kc], C1[s]);
        C2[s] = MFMA16(Ah, wsw[kc], C2[s]);
      }
    }
#pragma unroll
    for (int s = 0; s < 4; s++)
#pragma unroll
      for (int r = 0; r < 4; r++)
        m2[(s * 16 + q * 4 + r) * 136 + nt * 16 + l15] =
            f32_to_bf16(fmaxf(C1[s][r] + bias1, 0.f));
    __syncthreads();  // m2 ready
    // phase 2: C2 += m2 @ W1
#pragma unroll
    for (int kc = 0; kc < 4; kc++) {
#pragma unroll
      for (int s = 0; s < 4; s++) {
        short8 Am = *(const short8*)(&m2[(s * 16 + l15) * 136 + kc * 32 + q * 8]);
        C2[s] = MFMA16(Am, w1w[kc], C2[s]);
      }
    }
#pragma unroll
    for (int s = 0; s < 4; s++)
#pragma unroll
      for (int r = 0; r < 4; r++) C2[s][r] += bias2;
    if (doPool) {
      float m = -1e30f;
#pragma unroll
      for (int s = 0; s < 4; s++)
#pragma unroll
        for (int r = 0; r < 4; r++) m = fmaxf(m, C2[s][r]);
      m = fmaxf(m, __shfl_xor(m, 16, 64));
      m = fmaxf(m, __shfl_xor(m, 32, 64));
      if (lane < 16) atomicMax(&pool[b * 128 + nt * 16 + lane], f32_key(m));
    }
    __syncthreads();  // all m2 reads done -> reuse as out tile
#pragma unroll
    for (int s = 0; s < 4; s++)
#pragma unroll
      for (int r = 0; r < 4; r++)
        m2[(s * 16 + q * 4 + r) * 136 + nt * 16 + l15] = f32_to_bf16(C2[s][r]);
    __syncthreads();  // out tile ready
    {
      short8 v0 = *(const short8*)(&m2[r8 * 136 + cs8]);
      short8 v1 = *(const short8*)(&m2[r8 * 136 + cs8 + 8]);
      *(short8*)(hout + (size_t)(rowBase + r8) * 128 + cs8) = v0;
      *(short8*)(hout + (size_t)(rowBase + r8) * 128 + cs8 + 8) = v1;
    }
  }
}

extern "C" void kernel_launch(void* const* d_in, const int* in_sizes, int n_in,
                              void* d_out, int out_size, void* d_ws,
                              size_t ws_size, hipStream_t stream) {
  const float* p   = (const float*)d_in[0];
  const float* fcw = (const float*)d_in[1];
  const float* fcb = (const float*)d_in[2];
  const float* w0  = (const float*)d_in[3];
  const float* b0  = (const float*)d_in[4];
  const float* w1  = (const float*)d_in[5];
  const float* b1  = (const float*)d_in[6];
  const float* wsc = (const float*)d_in[7];
  float* out = (float*)d_out;

  char* wsp = (char*)d_ws;
  unsigned short* hA = (unsigned short*)wsp;
  unsigned short* hB = hA + (size_t)G_ALL * HD;
  unsigned short* B0t = hB + (size_t)G_ALL * HD;  // [128][256]
  unsigned short* W0t = B0t + 32768;   // [4][128][128]
  unsigned short* W1t = W0t + 65536;   // [5][128][128]
  unsigned short* WSt = W1t + 81920;   // [4][128][128]
  unsigned int* pool = (unsigned int*)(WSt + 65536);  // [4][2][128]
  float* Sp  = (float*)(pool + 1024);    // [3][128]
  float* bsp = Sp + 384;                 // [128]
  int* hist    = (int*)(bsp + 128);      // [2][16384] (becomes cursor)
  int* offsets = hist + 2 * NBINS;       // [2*16384 + 1] (+pad)
  int* order   = offsets + 2 * NBINS + 4;  // [131072]

  prep_kernel<<<1, 128, 0, stream>>>(fcw, fcb, wsc, Sp, bsp, pool, hist);
  wprep_kernel<<<960, 256, 0, stream>>>(w0, w1, wsc, B0t, W0t, W1t, WSt);
  index_kernel<<<512, 256, 0, stream>>>(p, hist);
  scan_kernel<<<1, 1024, 0, stream>>>(hist, offsets);
  fill_kernel<<<512, 256, 0, stream>>>(p, hist, order);

  stage0_kernel<<<512, 512, 0, stream>>>(p, fcw, fcb, B0t, W1t,
                                         b0, b1, Sp, bsp, hA, pool);
  unsigned short* hin = hA;
  unsigned short* hout = hB;
  for (int s = 1; s < 5; s++) {
    stageN_kernel<<<512, 512, 0, stream>>>(
        hin, hout, W0t + (s - 1) * 16384, W1t + s * 16384,
        WSt + (s - 1) * 16384, pool + (s - 1) * 256,
        b0 + s * HD, b1 + s * HD,
        w0 + (size_t)(s * 256 + 128) * HD, wsc + (size_t)(s * 256 + 128) * HD,
        pool + s * 256, (s < 4) ? 1 : 0);
    unsigned short* t = hin; hin = hout; hout = t;
  }
  gather_kernel<<<512, 256, 0, stream>>>(hin, offsets, order, out);
}

// Round 10
// 401.494 us; speedup vs baseline: 1.1389x; 1.1389x over previous
//
#include <hip/hip_runtime.h>
#include <hip/hip_bf16.h>

// LocalResnetPointnet v10: round-8 structure (separate fold kernels, minimal
// register pressure in stages so weights stay VGPR-resident) + coalesced-write
// gather (LDS bin transpose) + one fewer barrier per stageN tile (C -> At).

#define G_ALL 131072   // B*T
#define HD    128
#define NBINS 16384

typedef __attribute__((ext_vector_type(8))) short short8;
typedef __attribute__((ext_vector_type(4))) float f32x4;

#define MFMA16(a, b, c) __builtin_amdgcn_mfma_f32_16x16x32_bf16(a, b, c, 0, 0, 0)

__device__ __forceinline__ float bf16_to_f32(unsigned short u) {
  union { unsigned int u; float f; } v; v.u = ((unsigned int)u) << 16; return v.f;
}
__device__ __forceinline__ unsigned short f32_to_bf16(float f) {
  union { float f; unsigned int u; } v; v.f = f;
  unsigned int u = v.u;
  u += 0x7fffu + ((u >> 16) & 1u);   // RNE (no NaNs in this workload)
  return (unsigned short)(u >> 16);
}
// order-preserving float -> uint key for atomicMax
__device__ __forceinline__ unsigned int f32_key(float f) {
  union { float f; unsigned int u; } v; v.f = f;
  return (v.u & 0x80000000u) ? ~v.u : (v.u | 0x80000000u);
}
__device__ __forceinline__ float key_f32(unsigned int k) {
  union { unsigned int u; float f; } v;
  v.u = (k & 0x80000000u) ? (k & 0x7fffffffu) : ~k;
  return v.f;
}
__device__ __forceinline__ int bin_of(float p0, float p2) {
  float x = p0 / 1.101f + 0.5f;
  x = fminf(fmaxf(x, 0.0f), 1.0f - 1e-6f);
  int xi = (int)(x * 128.0f);
  float z = p2 / 1.101f + 0.5f;
  z = fminf(fmaxf(z, 0.0f), 1.0f - 1e-6f);
  int zi = (int)(z * 128.0f);
  return xi + 128 * zi;
}
__device__ __forceinline__ short8 relu8(short8 a) {
  short8 r;
#pragma unroll
  for (int e = 0; e < 8; e++) r[e] = a[e] < 0 ? (short)0 : a[e];
  return r;
}

// ---------------- prep: Sp = fcw@ws0, bsp = fcb@ws0, zero pools+hist -------
__global__ void prep_kernel(const float* __restrict__ fcw,
                            const float* __restrict__ fcb,
                            const float* __restrict__ ws0,
                            float* __restrict__ Sp, float* __restrict__ bsp,
                            unsigned int* __restrict__ pool,
                            int* __restrict__ hist) {
  int j = threadIdx.x;  // 128 threads
  for (int d = 0; d < 3; d++) {
    float s = 0.f;
    for (int ch = 0; ch < 256; ch++)
      s = fmaf(fcw[d * 256 + ch], ws0[ch * HD + j], s);
    Sp[d * HD + j] = s;
  }
  float s = 0.f;
  for (int ch = 0; ch < 256; ch++)
    s = fmaf(fcb[ch], ws0[ch * HD + j], s);
  bsp[j] = s;
  for (int k = j; k < 4 * 2 * 128; k += 128) pool[k] = 0u;
  for (int k = j; k < 2 * NBINS; k += 128) hist[k] = 0;
}

// ---------------- weight transform: transpose + bf16 cast ------------------
__global__ void wprep_kernel(const float* __restrict__ w0,
                             const float* __restrict__ w1,
                             const float* __restrict__ ws,
                             unsigned short* __restrict__ B0t,
                             unsigned short* __restrict__ W0t,
                             unsigned short* __restrict__ W1t,
                             unsigned short* __restrict__ WSt) {
  int gid = blockIdx.x * 256 + threadIdx.x;
  float v;
  unsigned short* dstp;
  int dst;
  if (gid < 32768) {                       // B0t: [n][k] from w0[0] (256x128)
    int n = gid >> 8, k = gid & 255;
    v = w0[k * 128 + n];
    dstp = B0t; dst = gid;
  } else if (gid < 98304) {                // W0t stages 1..4, rows 0..127
    int i = gid - 32768; int s = i >> 14; int n = (i >> 7) & 127; int k = i & 127;
    v = w0[(size_t)((s + 1) * 256 + k) * 128 + n];
    dstp = W0t; dst = i;
  } else if (gid < 180224) {               // W1t stages 0..4
    int i = gid - 98304; int s = i >> 14; int n = (i >> 7) & 127; int k = i & 127;
    v = w1[(size_t)(s * 128 + k) * 128 + n];
    dstp = W1t; dst = i;
  } else if (gid < 245760) {               // WSt stages 1..4, rows 0..127
    int i = gid - 180224; int s = i >> 14; int n = (i >> 7) & 127; int k = i & 127;
    v = ws[(size_t)((s + 1) * 256 + k) * 128 + n];
    dstp = WSt; dst = i;
  } else return;
  dstp[dst] = f32_to_bf16(v);
}

// ---------------- scatter pipeline -----------------------------------------
__global__ __launch_bounds__(256) void index_kernel(const float* __restrict__ p,
                                                    int* __restrict__ hist) {
  int g = blockIdx.x * 256 + threadIdx.x;
  int b = g >> 16;
  int idx = bin_of(p[3 * (size_t)g], p[3 * (size_t)g + 2]);
  atomicAdd(&hist[b * NBINS + idx], 1);
}

__global__ __launch_bounds__(1024) void scan_kernel(int* __restrict__ hist,
                                                    int* __restrict__ offsets) {
  __shared__ int sd[1024];
  int t = threadIdx.x;
  int vals[32];
  int s = 0;
#pragma unroll
  for (int i = 0; i < 32; i++) { vals[i] = hist[t * 32 + i]; s += vals[i]; }
  sd[t] = s;
  __syncthreads();
  for (int d = 1; d < 1024; d <<= 1) {
    int v = (t >= d) ? sd[t - d] : 0;
    __syncthreads();
    sd[t] += v;
    __syncthreads();
  }
  int run = sd[t] - s;  // exclusive prefix
#pragma unroll
  for (int i = 0; i < 32; i++) {
    offsets[t * 32 + i] = run;
    hist[t * 32 + i] = run;  // cursor copy (in-place)
    run += vals[i];
  }
  if (t == 1023) offsets[32768] = run;  // sentinel = G_ALL
}

__global__ __launch_bounds__(256) void fill_kernel(const float* __restrict__ p,
                                                   int* __restrict__ cursor,
                                                   int* __restrict__ order) {
  int g = blockIdx.x * 256 + threadIdx.x;
  int b = g >> 16;
  int idx = bin_of(p[3 * (size_t)g], p[3 * (size_t)g + 2]);
  int pos = atomicAdd(&cursor[b * NBINS + idx], 1);
  order[pos] = g;
}

// gather + mean: block = 64 bins; register accumulate -> LDS transpose ->
// fully-coalesced 256 B output stores (lane = bin).
__global__ __launch_bounds__(256) void gather_kernel(
    const unsigned short* __restrict__ c, const int* __restrict__ offsets,
    const int* __restrict__ order, float* __restrict__ out) {
  __shared__ float acc[129 * 65];  // [ch 0..127 | cnt row 128][bin 0..63]
  const int tid = threadIdx.x;
  const int wave = tid >> 6, lane = tid & 63;
  const int B0 = blockIdx.x * 64;          // global bin base (0..32767)
  const int b = B0 >> 14;

  for (int bi = 0; bi < 16; bi++) {
    const int binL = wave * 16 + bi;
    const int B = B0 + binL;
    const int st = offsets[B], en = offsets[B + 1];
    float a0 = 0.f, a1 = 0.f;
    for (int k = st; k < en; k++) {
      int g = order[k];
      unsigned int u = *(const unsigned int*)(c + (size_t)g * HD + lane * 2);
      a0 += bf16_to_f32((unsigned short)(u & 0xffffu));
      a1 += bf16_to_f32((unsigned short)(u >> 16));
    }
    acc[(2 * lane) * 65 + binL] = a0;
    acc[(2 * lane + 1) * 65 + binL] = a1;
    if (lane == 0) acc[128 * 65 + binL] = (float)(en - st);
  }
  __syncthreads();

  const size_t outBase = (size_t)b * HD * NBINS + (size_t)(B0 & (NBINS - 1));
  const float cnt = fmaxf(acc[128 * 65 + lane], 1.0f);
#pragma unroll
  for (int c2 = 0; c2 < 32; c2++) {
    int ch = wave * 32 + c2;
    out[outBase + (size_t)ch * NBINS + lane] = acc[ch * 65 + lane] / cnt;
  }
}

// ---------------- stage 0: fc_pos + block0 (weight-stationary MFMA) --------
// 8 waves; wave = nt (16 output ch). 512 blocks x 4 tiles of 64 rows.
__global__ __launch_bounds__(512, 4) void stage0_kernel(
    const float* __restrict__ p, const float* __restrict__ fcw,
    const float* __restrict__ fcb,
    const unsigned short* __restrict__ B0t,
    const unsigned short* __restrict__ W1t,
    const float* __restrict__ b0, const float* __restrict__ b1,
    const float* __restrict__ Sp, const float* __restrict__ bsp,
    unsigned short* __restrict__ hout, unsigned int* __restrict__ pool) {
  __shared__ float fcL[1024];                // fcw (768) + fcb (256)
  __shared__ float ptL[64 * 5];              // stride 5: conflict-free q-reads
  __shared__ unsigned short x0t[64 * 264];   // K=256 relu tile; reused as out tile
  __shared__ unsigned short m2[64 * 136];
  const int tid = threadIdx.x;
  const int lane = tid & 63;
  const int q = lane >> 4, l15 = lane & 15;
  const int nt = tid >> 6;                   // wave id = output-ch tile
  const int b = blockIdx.x >> 8;
  const int wrow = nt * 16 + l15;

  // weights -> registers (once per kernel): 8 + 4 short8 = 48 VGPRs
  short8 b0w[8], w1w[4];
#pragma unroll
  for (int kc = 0; kc < 8; kc++)
    b0w[kc] = *(const short8*)(B0t + (size_t)wrow * 256 + kc * 32 + q * 8);
#pragma unroll
  for (int kc = 0; kc < 4; kc++)
    w1w[kc] = *(const short8*)(W1t + (size_t)wrow * 128 + kc * 32 + q * 8);
  const float bias1 = b0[wrow];
  const float bias2 = bsp[wrow] + b1[wrow];
  const float sp0 = Sp[wrow], sp1 = Sp[128 + wrow], sp2 = Sp[256 + wrow];

  for (int k = tid; k < 1024; k += 512)
    fcL[k] = (k < 768) ? fcw[k] : fcb[k - 768];

  for (int it = 0; it < 4; it++) {
    const int rowBase = (blockIdx.x * 4 + it) * 64;
    __syncthreads();  // fcL ready (it0) / prev out-store complete
    if (tid < 192) ptL[(tid / 3) * 5 + (tid % 3)] = p[(size_t)rowBase * 3 + tid];
    // fc_pos: row = tid>>3; channels strided by 8 (bank-conflict-free fcL reads)
    {
      int row = tid >> 3, c8 = tid & 7;
      const float* pr = p + (size_t)(rowBase + row) * 3;
      float p0 = pr[0], p1 = pr[1], p2 = pr[2];
#pragma unroll
      for (int cc = 0; cc < 32; cc++) {
        int ch = c8 + cc * 8;
        float x = fcL[768 + ch] + p0 * fcL[ch] + p1 * fcL[256 + ch] + p2 * fcL[512 + ch];
        x0t[row * 264 + ch] = f32_to_bf16(fmaxf(x, 0.f));
      }
    }
    __syncthreads();  // x0t + ptL ready
    // phase 1: net = relu(x0) @ W0[0] + b0[0]  (K=256)
    f32x4 C1[4];
#pragma unroll
    for (int s = 0; s < 4; s++) C1[s] = (f32x4){bias1, bias1, bias1, bias1};
#pragma unroll
    for (int kc = 0; kc < 8; kc++) {
#pragma unroll
      for (int s = 0; s < 4; s++) {
        short8 Ar = *(const short8*)(&x0t[(s * 16 + l15) * 264 + kc * 32 + q * 8]);
        C1[s] = MFMA16(Ar, b0w[kc], C1[s]);
      }
    }
#pragma unroll
    for (int s = 0; s < 4; s++)
#pragma unroll
      for (int r = 0; r < 4; r++)
        m2[(s * 16 + q * 4 + r) * 136 + nt * 16 + l15] =
            f32_to_bf16(fmaxf(C1[s][r], 0.f));
    __syncthreads();  // m2 ready; x0t phase-1 reads done -> reuse as out tile
    // phase 2: h = m2 @ W1[0] + (p @ Sp + bsp + b1[0])
    f32x4 C2[4];
#pragma unroll
    for (int s = 0; s < 4; s++)
#pragma unroll
      for (int r = 0; r < 4; r++) {
        int row = s * 16 + q * 4 + r;
        C2[s][r] = bias2 + ptL[row * 5] * sp0 + ptL[row * 5 + 1] * sp1 +
                   ptL[row * 5 + 2] * sp2;
      }
#pragma unroll
    for (int kc = 0; kc < 4; kc++) {
#pragma unroll
      for (int s = 0; s < 4; s++) {
        short8 Am = *(const short8*)(&m2[(s * 16 + l15) * 136 + kc * 32 + q * 8]);
        C2[s] = MFMA16(Am, w1w[kc], C2[s]);
      }
    }
#pragma unroll
    for (int s = 0; s < 4; s++)
#pragma unroll
      for (int r = 0; r < 4; r++)
        x0t[(s * 16 + q * 4 + r) * 136 + nt * 16 + l15] = f32_to_bf16(C2[s][r]);
    {
      float m = -1e30f;
#pragma unroll
      for (int s = 0; s < 4; s++)
#pragma unroll
        for (int r = 0; r < 4; r++) m = fmaxf(m, C2[s][r]);
      m = fmaxf(m, __shfl_xor(m, 16, 64));
      m = fmaxf(m, __shfl_xor(m, 32, 64));
      if (lane < 16) atomicMax(&pool[b * 128 + nt * 16 + lane], f32_key(m));
    }
    __syncthreads();  // out tile ready
    {
      int r = tid >> 3, cs = (tid & 7) * 16;
      short8 v0 = *(const short8*)(&x0t[r * 136 + cs]);
      short8 v1 = *(const short8*)(&x0t[r * 136 + cs + 8]);
      *(short8*)(hout + (size_t)(rowBase + r) * 128 + cs) = v0;
      *(short8*)(hout + (size_t)(rowBase + r) * 128 + cs + 8) = v1;
    }
  }
}

// ---------------- stages 1..4 (weight-stationary MFMA) ---------------------
// 8 waves; wave = nt. 512 blocks x 4 tiles of 64 rows. WS fused in phase 1.
// Output tile written into At (all At reads done by the m2-ready barrier).
__global__ __launch_bounds__(512, 4) void stageN_kernel(
    const unsigned short* __restrict__ hin, unsigned short* __restrict__ hout,
    const unsigned short* __restrict__ W0t,
    const unsigned short* __restrict__ W1t,
    const unsigned short* __restrict__ WSt,
    const float* __restrict__ b0e, const float* __restrict__ bse,
    unsigned int* __restrict__ pool, int doPool) {
  __shared__ unsigned short At[64 * 136];   // H tile; reused as output tile
  __shared__ unsigned short m2[64 * 136];   // relu(net)
  const int tid = threadIdx.x;
  const int lane = tid & 63;
  const int q = lane >> 4, l15 = lane & 15;
  const int nt = tid >> 6;
  const int b = blockIdx.x >> 8;
  const int wrow = nt * 16 + l15;

  // 12 short8 = 48 VGPRs of weights
  short8 w0w[4], w1w[4], wsw[4];
#pragma unroll
  for (int kc = 0; kc < 4; kc++) {
    w0w[kc] = *(const short8*)(W0t + (size_t)wrow * 128 + kc * 32 + q * 8);
    w1w[kc] = *(const short8*)(W1t + (size_t)wrow * 128 + kc * 32 + q * 8);
    wsw[kc] = *(const short8*)(WSt + (size_t)wrow * 128 + kc * 32 + q * 8);
  }
  const float bias1 = b0e[b * 128 + wrow];
  const float bias2 = bse[b * 128 + wrow];
  const int r8 = tid >> 3, cs8 = (tid & 7) * 16;

  for (int it = 0; it < 4; it++) {
    const int rowBase = (blockIdx.x * 4 + it) * 64;
    __syncthreads();  // prev store complete -> At writable
    {
      const size_t gb = ((size_t)rowBase + r8) * 128 + cs8;
      short8 v0 = *(const short8*)(hin + gb);
      short8 v1 = *(const short8*)(hin + gb + 8);
      *(short8*)(&At[r8 * 136 + cs8]) = v0;
      *(short8*)(&At[r8 * 136 + cs8 + 8]) = v1;
    }
    __syncthreads();  // At ready
    // phase 1: C1 = relu(H)@W0 + b0e ; C2 = H@WS + bse (shortcut fused)
    f32x4 C1[4], C2[4];
#pragma unroll
    for (int s = 0; s < 4; s++) {
      C1[s] = (f32x4){bias1, bias1, bias1, bias1};
      C2[s] = (f32x4){bias2, bias2, bias2, bias2};
    }
#pragma unroll
    for (int kc = 0; kc < 4; kc++) {
#pragma unroll
      for (int s = 0; s < 4; s++) {
        short8 Ah = *(const short8*)(&At[(s * 16 + l15) * 136 + kc * 32 + q * 8]);
        short8 Ar = relu8(Ah);
        C1[s] = MFMA16(Ar, w0w[kc], C1[s]);
        C2[s] = MFMA16(Ah, wsw[kc], C2[s]);
      }
    }
#pragma unroll
    for (int s = 0; s < 4; s++)
#pragma unroll
      for (int r = 0; r < 4; r++)
        m2[(s * 16 + q * 4 + r) * 136 + nt * 16 + l15] =
            f32_to_bf16(fmaxf(C1[s][r], 0.f));
    __syncthreads();  // m2 ready; implies all At reads done
    // phase 2: C2 += m2 @ W1
#pragma unroll
    for (int kc = 0; kc < 4; kc++) {
#pragma unroll
      for (int s = 0; s < 4; s++) {
        short8 Am = *(const short8*)(&m2[(s * 16 + l15) * 136 + kc * 32 + q * 8]);
        C2[s] = MFMA16(Am, w1w[kc], C2[s]);
      }
    }
    if (doPool) {
      float m = -1e30f;
#pragma unroll
      for (int s = 0; s < 4; s++)
#pragma unroll
        for (int r = 0; r < 4; r++) m = fmaxf(m, C2[s][r]);
      m = fmaxf(m, __shfl_xor(m, 16, 64));
      m = fmaxf(m, __shfl_xor(m, 32, 64));
      if (lane < 16) atomicMax(&pool[b * 128 + nt * 16 + lane], f32_key(m));
    }
    // write output into At (no barrier needed: At reads finished at m2-ready)
#pragma unroll
    for (int s = 0; s < 4; s++)
#pragma unroll
      for (int r = 0; r < 4; r++)
        At[(s * 16 + q * 4 + r) * 136 + nt * 16 + l15] = f32_to_bf16(C2[s][r]);
    __syncthreads();  // out tile ready
    {
      short8 v0 = *(const short8*)(&At[r8 * 136 + cs8]);
      short8 v1 = *(const short8*)(&At[r8 * 136 + cs8 + 8]);
      *(short8*)(hout + (size_t)(rowBase + r8) * 128 + cs8) = v0;
      *(short8*)(hout + (size_t)(rowBase + r8) * 128 + cs8 + 8) = v1;
    }
  }
}

// ---------------- fold: per-batch effective biases from pool ---------------
__global__ void fold_kernel(const unsigned int* __restrict__ pool,
                            const float* __restrict__ b0s,
                            const float* __restrict__ b1s,
                            const float* __restrict__ w0hi,  // f32, rows 128..255
                            const float* __restrict__ wshi,
                            float* __restrict__ b0e, float* __restrict__ bse) {
  __shared__ float ps[256];
  int tid = threadIdx.x;  // 256
  int b = tid >> 7, j = tid & 127;
  ps[tid] = key_f32(pool[tid]);
  __syncthreads();
  float a0 = b0s[j], a1 = b1s[j];
  for (int ch = 0; ch < 128; ch++) {
    float pv = ps[b * 128 + ch];
    a0 = fmaf(fmaxf(pv, 0.f), w0hi[ch * HD + j], a0);
    a1 = fmaf(pv, wshi[ch * HD + j], a1);
  }
  b0e[b * 128 + j] = a0;
  bse[b * 128 + j] = a1;
}

extern "C" void kernel_launch(void* const* d_in, const int* in_sizes, int n_in,
                              void* d_out, int out_size, void* d_ws,
                              size_t ws_size, hipStream_t stream) {
  const float* p   = (const float*)d_in[0];
  const float* fcw = (const float*)d_in[1];
  const float* fcb = (const float*)d_in[2];
  const float* w0  = (const float*)d_in[3];
  const float* b0  = (const float*)d_in[4];
  const float* w1  = (const float*)d_in[5];
  const float* b1  = (const float*)d_in[6];
  const float* wsc = (const float*)d_in[7];
  float* out = (float*)d_out;

  char* wsp = (char*)d_ws;
  unsigned short* hA = (unsigned short*)wsp;
  unsigned short* hB = hA + (size_t)G_ALL * HD;
  unsigned short* B0t = hB + (size_t)G_ALL * HD;  // [128][256]
  unsigned short* W0t = B0t + 32768;   // [4][128][128]
  unsigned short* W1t = W0t + 65536;   // [5][128][128]
  unsigned short* WSt = W1t + 81920;   // [4][128][128]
  unsigned int* pool = (unsigned int*)(WSt + 65536);  // [4][2][128]
  float* b0e = (float*)(pool + 1024);    // [4][2][128]
  float* bse = b0e + 1024;
  float* Sp  = bse + 1024;               // [3][128]
  float* bsp = Sp + 384;                 // [128]
  int* hist    = (int*)(bsp + 128);      // [2][16384] (becomes cursor)
  int* offsets = hist + 2 * NBINS;       // [2*16384 + 1] (+pad)
  int* order   = offsets + 2 * NBINS + 4;  // [131072]

  prep_kernel<<<1, 128, 0, stream>>>(fcw, fcb, wsc, Sp, bsp, pool, hist);
  wprep_kernel<<<960, 256, 0, stream>>>(w0, w1, wsc, B0t, W0t, W1t, WSt);
  index_kernel<<<512, 256, 0, stream>>>(p, hist);
  scan_kernel<<<1, 1024, 0, stream>>>(hist, offsets);
  fill_kernel<<<512, 256, 0, stream>>>(p, hist, order);

  stage0_kernel<<<512, 512, 0, stream>>>(p, fcw, fcb, B0t, W1t,
                                         b0, b1, Sp, bsp, hA, pool);
  unsigned short* hin = hA;
  unsigned short* hout = hB;
  for (int s = 1; s < 5; s++) {
    fold_kernel<<<1, 256, 0, stream>>>(
        pool + (s - 1) * 256, b0 + s * HD, b1 + s * HD,
        w0 + (size_t)(s * 256 + 128) * HD, wsc + (size_t)(s * 256 + 128) * HD,
        b0e + (s - 1) * 256, bse + (s - 1) * 256);
    stageN_kernel<<<512, 512, 0, stream>>>(
        hin, hout, W0t + (s - 1) * 16384, W1t + s * 16384,
        WSt + (s - 1) * 16384, b0e + (s - 1) * 256, bse + (s - 1) * 256,
        pool + s * 256, (s < 4) ? 1 : 0);
    unsigned short* t = hin; hin = hout; hout = t;
  }
  gather_kernel<<<512, 256, 0, stream>>>(hin, offsets, order, out);
}

// Round 11
// 357.635 us; speedup vs baseline: 1.2786x; 1.1226x over previous
//
#include <hip/hip_runtime.h>
#include <hip/hip_bf16.h>

// LocalResnetPointnet v11: r10 stages + rank-scatter stage-4 output so the
// gather reads sorted rows sequentially (no order[] indirection), merged
// wprep+index launch.

#define G_ALL 131072   // B*T
#define HD    128
#define NBINS 16384

typedef __attribute__((ext_vector_type(8))) short short8;
typedef __attribute__((ext_vector_type(4))) float f32x4;

#define MFMA16(a, b, c) __builtin_amdgcn_mfma_f32_16x16x32_bf16(a, b, c, 0, 0, 0)

__device__ __forceinline__ float bf16_to_f32(unsigned short u) {
  union { unsigned int u; float f; } v; v.u = ((unsigned int)u) << 16; return v.f;
}
__device__ __forceinline__ unsigned short f32_to_bf16(float f) {
  union { float f; unsigned int u; } v; v.f = f;
  unsigned int u = v.u;
  u += 0x7fffu + ((u >> 16) & 1u);   // RNE (no NaNs in this workload)
  return (unsigned short)(u >> 16);
}
// order-preserving float -> uint key for atomicMax
__device__ __forceinline__ unsigned int f32_key(float f) {
  union { float f; unsigned int u; } v; v.f = f;
  return (v.u & 0x80000000u) ? ~v.u : (v.u | 0x80000000u);
}
__device__ __forceinline__ float key_f32(unsigned int k) {
  union { unsigned int u; float f; } v;
  v.u = (k & 0x80000000u) ? (k & 0x7fffffffu) : ~k;
  return v.f;
}
__device__ __forceinline__ int bin_of(float p0, float p2) {
  float x = p0 / 1.101f + 0.5f;
  x = fminf(fmaxf(x, 0.0f), 1.0f - 1e-6f);
  int xi = (int)(x * 128.0f);
  float z = p2 / 1.101f + 0.5f;
  z = fminf(fmaxf(z, 0.0f), 1.0f - 1e-6f);
  int zi = (int)(z * 128.0f);
  return xi + 128 * zi;
}
__device__ __forceinline__ short8 relu8(short8 a) {
  short8 r;
#pragma unroll
  for (int e = 0; e < 8; e++) r[e] = a[e] < 0 ? (short)0 : a[e];
  return r;
}

// ---------------- prep: zero hist/pool; block 0 computes Sp/bsp ------------
__global__ __launch_bounds__(128) void prep_kernel(
    const float* __restrict__ fcw, const float* __restrict__ fcb,
    const float* __restrict__ ws0, float* __restrict__ Sp,
    float* __restrict__ bsp, unsigned int* __restrict__ pool,
    int* __restrict__ hist) {
  int t = blockIdx.x * 128 + threadIdx.x;  // 16384 threads
  hist[t * 2] = 0;
  hist[t * 2 + 1] = 0;
  if (t < 1024) pool[t] = 0u;
  if (blockIdx.x == 0) {
    int j = threadIdx.x;
    for (int d = 0; d < 3; d++) {
      float s = 0.f;
      for (int ch = 0; ch < 256; ch++)
        s = fmaf(fcw[d * 256 + ch], ws0[ch * HD + j], s);
      Sp[d * HD + j] = s;
    }
    float s = 0.f;
    for (int ch = 0; ch < 256; ch++)
      s = fmaf(fcb[ch], ws0[ch * HD + j], s);
    bsp[j] = s;
  }
}

// ---------------- merged: weight transpose/cast + bin histogram ------------
__global__ __launch_bounds__(256) void wi_kernel(
    const float* __restrict__ w0, const float* __restrict__ w1,
    const float* __restrict__ ws, const float* __restrict__ p,
    unsigned short* __restrict__ B0t, unsigned short* __restrict__ W0t,
    unsigned short* __restrict__ W1t, unsigned short* __restrict__ WSt,
    int* __restrict__ hist) {
  int gid = blockIdx.x * 256 + threadIdx.x;
  if (gid >= 245760) {                     // index part: 131072 threads
    int g = gid - 245760;
    int b = g >> 16;
    int idx = bin_of(p[3 * (size_t)g], p[3 * (size_t)g + 2]);
    atomicAdd(&hist[b * NBINS + idx], 1);
    return;
  }
  float v;
  unsigned short* dstp;
  int dst;
  if (gid < 32768) {                       // B0t: [n][k] from w0[0] (256x128)
    int n = gid >> 8, k = gid & 255;
    v = w0[k * 128 + n];
    dstp = B0t; dst = gid;
  } else if (gid < 98304) {                // W0t stages 1..4, rows 0..127
    int i = gid - 32768; int s = i >> 14; int n = (i >> 7) & 127; int k = i & 127;
    v = w0[(size_t)((s + 1) * 256 + k) * 128 + n];
    dstp = W0t; dst = i;
  } else if (gid < 180224) {               // W1t stages 0..4
    int i = gid - 98304; int s = i >> 14; int n = (i >> 7) & 127; int k = i & 127;
    v = w1[(size_t)(s * 128 + k) * 128 + n];
    dstp = W1t; dst = i;
  } else {                                 // WSt stages 1..4, rows 0..127
    int i = gid - 180224; int s = i >> 14; int n = (i >> 7) & 127; int k = i & 127;
    v = ws[(size_t)((s + 1) * 256 + k) * 128 + n];
    dstp = WSt; dst = i;
  }
  dstp[dst] = f32_to_bf16(v);
}

__global__ __launch_bounds__(1024) void scan_kernel(int* __restrict__ hist,
                                                    int* __restrict__ offsets) {
  __shared__ int sd[1024];
  int t = threadIdx.x;
  int vals[32];
  int s = 0;
#pragma unroll
  for (int i = 0; i < 32; i++) { vals[i] = hist[t * 32 + i]; s += vals[i]; }
  sd[t] = s;
  __syncthreads();
  for (int d = 1; d < 1024; d <<= 1) {
    int v = (t >= d) ? sd[t - d] : 0;
    __syncthreads();
    sd[t] += v;
    __syncthreads();
  }
  int run = sd[t] - s;  // exclusive prefix
#pragma unroll
  for (int i = 0; i < 32; i++) {
    offsets[t * 32 + i] = run;
    hist[t * 32 + i] = run;  // cursor copy (in-place)
    run += vals[i];
  }
  if (t == 1023) offsets[32768] = run;  // sentinel = G_ALL
}

__global__ __launch_bounds__(256) void fill_kernel(const float* __restrict__ p,
                                                   int* __restrict__ cursor,
                                                   int* __restrict__ rank) {
  int g = blockIdx.x * 256 + threadIdx.x;
  int b = g >> 16;
  int idx = bin_of(p[3 * (size_t)g], p[3 * (size_t)g + 2]);
  int pos = atomicAdd(&cursor[b * NBINS + idx], 1);
  rank[g] = pos;
}

// gather + mean over SORTED rows: block = 64 bins, rows sequential, no
// indirection. Register accumulate -> LDS transpose -> coalesced stores.
__global__ __launch_bounds__(256) void gather_kernel(
    const unsigned short* __restrict__ cS, const int* __restrict__ offsets,
    float* __restrict__ out) {
  __shared__ float acc[129 * 65];  // [ch 0..127 | cnt row 128][bin 0..63]
  const int tid = threadIdx.x;
  const int wave = tid >> 6, lane = tid & 63;
  const int B0 = blockIdx.x * 64;          // global bin base (0..32767)
  const int b = B0 >> 14;

  for (int bi = 0; bi < 16; bi++) {
    const int binL = wave * 16 + bi;
    const int B = B0 + binL;
    const int st = offsets[B], en = offsets[B + 1];
    float a0 = 0.f, a1 = 0.f;
    int k = st;
    for (; k + 2 <= en; k += 2) {
      unsigned int u0 = *(const unsigned int*)(cS + (size_t)k * HD + lane * 2);
      unsigned int u1 = *(const unsigned int*)(cS + (size_t)(k + 1) * HD + lane * 2);
      a0 += bf16_to_f32((unsigned short)(u0 & 0xffffu));
      a1 += bf16_to_f32((unsigned short)(u0 >> 16));
      a0 += bf16_to_f32((unsigned short)(u1 & 0xffffu));
      a1 += bf16_to_f32((unsigned short)(u1 >> 16));
    }
    if (k < en) {
      unsigned int u = *(const unsigned int*)(cS + (size_t)k * HD + lane * 2);
      a0 += bf16_to_f32((unsigned short)(u & 0xffffu));
      a1 += bf16_to_f32((unsigned short)(u >> 16));
    }
    acc[(2 * lane) * 65 + binL] = a0;
    acc[(2 * lane + 1) * 65 + binL] = a1;
    if (lane == 0) acc[128 * 65 + binL] = (float)(en - st);
  }
  __syncthreads();

  const size_t outBase = (size_t)b * HD * NBINS + (size_t)(B0 & (NBINS - 1));
  const float cnt = fmaxf(acc[128 * 65 + lane], 1.0f);
#pragma unroll
  for (int c2 = 0; c2 < 32; c2++) {
    int ch = wave * 32 + c2;
    out[outBase + (size_t)ch * NBINS + lane] = acc[ch * 65 + lane] / cnt;
  }
}

// ---------------- stage 0: fc_pos + block0 (weight-stationary MFMA) --------
// 8 waves; wave = nt (16 output ch). 512 blocks x 4 tiles of 64 rows.
__global__ __launch_bounds__(512, 4) void stage0_kernel(
    const float* __restrict__ p, const float* __restrict__ fcw,
    const float* __restrict__ fcb,
    const unsigned short* __restrict__ B0t,
    const unsigned short* __restrict__ W1t,
    const float* __restrict__ b0, const float* __restrict__ b1,
    const float* __restrict__ Sp, const float* __restrict__ bsp,
    unsigned short* __restrict__ hout, unsigned int* __restrict__ pool) {
  __shared__ float fcL[1024];                // fcw (768) + fcb (256)
  __shared__ float ptL[64 * 5];              // stride 5: conflict-free q-reads
  __shared__ unsigned short x0t[64 * 264];   // K=256 relu tile; reused as out tile
  __shared__ unsigned short m2[64 * 136];
  const int tid = threadIdx.x;
  const int lane = tid & 63;
  const int q = lane >> 4, l15 = lane & 15;
  const int nt = tid >> 6;                   // wave id = output-ch tile
  const int b = blockIdx.x >> 8;
  const int wrow = nt * 16 + l15;

  // weights -> registers (once per kernel): 8 + 4 short8 = 48 VGPRs
  short8 b0w[8], w1w[4];
#pragma unroll
  for (int kc = 0; kc < 8; kc++)
    b0w[kc] = *(const short8*)(B0t + (size_t)wrow * 256 + kc * 32 + q * 8);
#pragma unroll
  for (int kc = 0; kc < 4; kc++)
    w1w[kc] = *(const short8*)(W1t + (size_t)wrow * 128 + kc * 32 + q * 8);
  const float bias1 = b0[wrow];
  const float bias2 = bsp[wrow] + b1[wrow];
  const float sp0 = Sp[wrow], sp1 = Sp[128 + wrow], sp2 = Sp[256 + wrow];

  for (int k = tid; k < 1024; k += 512)
    fcL[k] = (k < 768) ? fcw[k] : fcb[k - 768];

  for (int it = 0; it < 4; it++) {
    const int rowBase = (blockIdx.x * 4 + it) * 64;
    __syncthreads();  // fcL ready (it0) / prev out-store complete
    if (tid < 192) ptL[(tid / 3) * 5 + (tid % 3)] = p[(size_t)rowBase * 3 + tid];
    // fc_pos: row = tid>>3; channels strided by 8 (bank-conflict-free fcL reads)
    {
      int row = tid >> 3, c8 = tid & 7;
      const float* pr = p + (size_t)(rowBase + row) * 3;
      float p0 = pr[0], p1 = pr[1], p2 = pr[2];
#pragma unroll
      for (int cc = 0; cc < 32; cc++) {
        int ch = c8 + cc * 8;
        float x = fcL[768 + ch] + p0 * fcL[ch] + p1 * fcL[256 + ch] + p2 * fcL[512 + ch];
        x0t[row * 264 + ch] = f32_to_bf16(fmaxf(x, 0.f));
      }
    }
    __syncthreads();  // x0t + ptL ready
    // phase 1: net = relu(x0) @ W0[0] + b0[0]  (K=256)
    f32x4 C1[4];
#pragma unroll
    for (int s = 0; s < 4; s++) C1[s] = (f32x4){bias1, bias1, bias1, bias1};
#pragma unroll
    for (int kc = 0; kc < 8; kc++) {
#pragma unroll
      for (int s = 0; s < 4; s++) {
        short8 Ar = *(const short8*)(&x0t[(s * 16 + l15) * 264 + kc * 32 + q * 8]);
        C1[s] = MFMA16(Ar, b0w[kc], C1[s]);
      }
    }
#pragma unroll
    for (int s = 0; s < 4; s++)
#pragma unroll
      for (int r = 0; r < 4; r++)
        m2[(s * 16 + q * 4 + r) * 136 + nt * 16 + l15] =
            f32_to_bf16(fmaxf(C1[s][r], 0.f));
    __syncthreads();  // m2 ready; x0t phase-1 reads done -> reuse as out tile
    // phase 2: h = m2 @ W1[0] + (p @ Sp + bsp + b1[0])
    f32x4 C2[4];
#pragma unroll
    for (int s = 0; s < 4; s++)
#pragma unroll
      for (int r = 0; r < 4; r++) {
        int row = s * 16 + q * 4 + r;
        C2[s][r] = bias2 + ptL[row * 5] * sp0 + ptL[row * 5 + 1] * sp1 +
                   ptL[row * 5 + 2] * sp2;
      }
#pragma unroll
    for (int kc = 0; kc < 4; kc++) {
#pragma unroll
      for (int s = 0; s < 4; s++) {
        short8 Am = *(const short8*)(&m2[(s * 16 + l15) * 136 + kc * 32 + q * 8]);
        C2[s] = MFMA16(Am, w1w[kc], C2[s]);
      }
    }
#pragma unroll
    for (int s = 0; s < 4; s++)
#pragma unroll
      for (int r = 0; r < 4; r++)
        x0t[(s * 16 + q * 4 + r) * 136 + nt * 16 + l15] = f32_to_bf16(C2[s][r]);
    {
      float m = -1e30f;
#pragma unroll
      for (int s = 0; s < 4; s++)
#pragma unroll
        for (int r = 0; r < 4; r++) m = fmaxf(m, C2[s][r]);
      m = fmaxf(m, __shfl_xor(m, 16, 64));
      m = fmaxf(m, __shfl_xor(m, 32, 64));
      if (lane < 16) atomicMax(&pool[b * 128 + nt * 16 + lane], f32_key(m));
    }
    __syncthreads();  // out tile ready
    {
      int r = tid >> 3, cs = (tid & 7) * 16;
      short8 v0 = *(const short8*)(&x0t[r * 136 + cs]);
      short8 v1 = *(const short8*)(&x0t[r * 136 + cs + 8]);
      *(short8*)(hout + (size_t)(rowBase + r) * 128 + cs) = v0;
      *(short8*)(hout + (size_t)(rowBase + r) * 128 + cs + 8) = v1;
    }
  }
}

// ---------------- stages 1..4 (weight-stationary MFMA) ---------------------
// 8 waves; wave = nt. 512 blocks x 4 tiles of 64 rows. WS fused in phase 1.
// Output tile written into At. Stage 4 scatters rows to rank[] positions.
__global__ __launch_bounds__(512, 4) void stageN_kernel(
    const unsigned short* __restrict__ hin, unsigned short* __restrict__ hout,
    const unsigned short* __restrict__ W0t,
    const unsigned short* __restrict__ W1t,
    const unsigned short* __restrict__ WSt,
    const float* __restrict__ b0e, const float* __restrict__ bse,
    unsigned int* __restrict__ pool, int doPool,
    const int* __restrict__ rank, int useRank) {
  __shared__ unsigned short At[64 * 136];   // H tile; reused as output tile
  __shared__ unsigned short m2[64 * 136];   // relu(net)
  const int tid = threadIdx.x;
  const int lane = tid & 63;
  const int q = lane >> 4, l15 = lane & 15;
  const int nt = tid >> 6;
  const int b = blockIdx.x >> 8;
  const int wrow = nt * 16 + l15;

  // 12 short8 = 48 VGPRs of weights
  short8 w0w[4], w1w[4], wsw[4];
#pragma unroll
  for (int kc = 0; kc < 4; kc++) {
    w0w[kc] = *(const short8*)(W0t + (size_t)wrow * 128 + kc * 32 + q * 8);
    w1w[kc] = *(const short8*)(W1t + (size_t)wrow * 128 + kc * 32 + q * 8);
    wsw[kc] = *(const short8*)(WSt + (size_t)wrow * 128 + kc * 32 + q * 8);
  }
  const float bias1 = b0e[b * 128 + wrow];
  const float bias2 = bse[b * 128 + wrow];
  const int r8 = tid >> 3, cs8 = (tid & 7) * 16;

  for (int it = 0; it < 4; it++) {
    const int rowBase = (blockIdx.x * 4 + it) * 64;
    __syncthreads();  // prev store complete -> At writable
    {
      const size_t gb = ((size_t)rowBase + r8) * 128 + cs8;
      short8 v0 = *(const short8*)(hin + gb);
      short8 v1 = *(const short8*)(hin + gb + 8);
      *(short8*)(&At[r8 * 136 + cs8]) = v0;
      *(short8*)(&At[r8 * 136 + cs8 + 8]) = v1;
    }
    __syncthreads();  // At ready
    // phase 1: C1 = relu(H)@W0 + b0e ; C2 = H@WS + bse (shortcut fused)
    f32x4 C1[4], C2[4];
#pragma unroll
    for (int s = 0; s < 4; s++) {
      C1[s] = (f32x4){bias1, bias1, bias1, bias1};
      C2[s] = (f32x4){bias2, bias2, bias2, bias2};
    }
#pragma unroll
    for (int kc = 0; kc < 4; kc++) {
#pragma unroll
      for (int s = 0; s < 4; s++) {
        short8 Ah = *(const short8*)(&At[(s * 16 + l15) * 136 + kc * 32 + q * 8]);
        short8 Ar = relu8(Ah);
        C1[s] = MFMA16(Ar, w0w[kc], C1[s]);
        C2[s] = MFMA16(Ah, wsw[kc], C2[s]);
      }
    }
#pragma unroll
    for (int s = 0; s < 4; s++)
#pragma unroll
      for (int r = 0; r < 4; r++)
        m2[(s * 16 + q * 4 + r) * 136 + nt * 16 + l15] =
            f32_to_bf16(fmaxf(C1[s][r], 0.f));
    __syncthreads();  // m2 ready; implies all At reads done
    // phase 2: C2 += m2 @ W1
#pragma unroll
    for (int kc = 0; kc < 4; kc++) {
#pragma unroll
      for (int s = 0; s < 4; s++) {
        short8 Am = *(const short8*)(&m2[(s * 16 + l15) * 136 + kc * 32 + q * 8]);
        C2[s] = MFMA16(Am, w1w[kc], C2[s]);
      }
    }
    if (doPool) {
      float m = -1e30f;
#pragma unroll
      for (int s = 0; s < 4; s++)
#pragma unroll
        for (int r = 0; r < 4; r++) m = fmaxf(m, C2[s][r]);
      m = fmaxf(m, __shfl_xor(m, 16, 64));
      m = fmaxf(m, __shfl_xor(m, 32, 64));
      if (lane < 16) atomicMax(&pool[b * 128 + nt * 16 + lane], f32_key(m));
    }
    // write output into At (no barrier needed: At reads finished at m2-ready)
#pragma unroll
    for (int s = 0; s < 4; s++)
#pragma unroll
      for (int r = 0; r < 4; r++)
        At[(s * 16 + q * 4 + r) * 136 + nt * 16 + l15] = f32_to_bf16(C2[s][r]);
    __syncthreads();  // out tile ready
    {
      int destRow = rowBase + r8;
      if (useRank) destRow = rank[destRow];  // sorted scatter (stage 4)
      short8 v0 = *(const short8*)(&At[r8 * 136 + cs8]);
      short8 v1 = *(const short8*)(&At[r8 * 136 + cs8 + 8]);
      *(short8*)(hout + (size_t)destRow * 128 + cs8) = v0;
      *(short8*)(hout + (size_t)destRow * 128 + cs8 + 8) = v1;
    }
  }
}

// ---------------- fold: per-batch effective biases from pool ---------------
__global__ void fold_kernel(const unsigned int* __restrict__ pool,
                            const float* __restrict__ b0s,
                            const float* __restrict__ b1s,
                            const float* __restrict__ w0hi,  // f32, rows 128..255
                            const float* __restrict__ wshi,
                            float* __restrict__ b0e, float* __restrict__ bse) {
  __shared__ float ps[256];
  int tid = threadIdx.x;  // 256
  int b = tid >> 7, j = tid & 127;
  ps[tid] = key_f32(pool[tid]);
  __syncthreads();
  float a0 = b0s[j], a1 = b1s[j];
  for (int ch = 0; ch < 128; ch++) {
    float pv = ps[b * 128 + ch];
    a0 = fmaf(fmaxf(pv, 0.f), w0hi[ch * HD + j], a0);
    a1 = fmaf(pv, wshi[ch * HD + j], a1);
  }
  b0e[b * 128 + j] = a0;
  bse[b * 128 + j] = a1;
}

extern "C" void kernel_launch(void* const* d_in, const int* in_sizes, int n_in,
                              void* d_out, int out_size, void* d_ws,
                              size_t ws_size, hipStream_t stream) {
  const float* p   = (const float*)d_in[0];
  const float* fcw = (const float*)d_in[1];
  const float* fcb = (const float*)d_in[2];
  const float* w0  = (const float*)d_in[3];
  const float* b0  = (const float*)d_in[4];
  const float* w1  = (const float*)d_in[5];
  const float* b1  = (const float*)d_in[6];
  const float* wsc = (const float*)d_in[7];
  float* out = (float*)d_out;

  char* wsp = (char*)d_ws;
  unsigned short* hA = (unsigned short*)wsp;
  unsigned short* hB = hA + (size_t)G_ALL * HD;
  unsigned short* B0t = hB + (size_t)G_ALL * HD;  // [128][256]
  unsigned short* W0t = B0t + 32768;   // [4][128][128]
  unsigned short* W1t = W0t + 65536;   // [5][128][128]
  unsigned short* WSt = W1t + 81920;   // [4][128][128]
  unsigned int* pool = (unsigned int*)(WSt + 65536);  // [4][2][128]
  float* b0e = (float*)(pool + 1024);    // [4][2][128]
  float* bse = b0e + 1024;
  float* Sp  = bse + 1024;               // [3][128]
  float* bsp = Sp + 384;                 // [128]
  int* hist    = (int*)(bsp + 128);      // [2][16384] (becomes cursor)
  int* offsets = hist + 2 * NBINS;       // [2*16384 + 1] (+pad)
  int* rank    = offsets + 2 * NBINS + 4;  // [131072]

  prep_kernel<<<128, 128, 0, stream>>>(fcw, fcb, wsc, Sp, bsp, pool, hist);
  wi_kernel<<<1472, 256, 0, stream>>>(w0, w1, wsc, p, B0t, W0t, W1t, WSt, hist);
  scan_kernel<<<1, 1024, 0, stream>>>(hist, offsets);
  fill_kernel<<<512, 256, 0, stream>>>(p, hist, rank);

  stage0_kernel<<<512, 512, 0, stream>>>(p, fcw, fcb, B0t, W1t,
                                         b0, b1, Sp, bsp, hA, pool);
  unsigned short* hin = hA;
  unsigned short* hout = hB;
  for (int s = 1; s < 5; s++) {
    fold_kernel<<<1, 256, 0, stream>>>(
        pool + (s - 1) * 256, b0 + s * HD, b1 + s * HD,
        w0 + (size_t)(s * 256 + 128) * HD, wsc + (size_t)(s * 256 + 128) * HD,
        b0e + (s - 1) * 256, bse + (s - 1) * 256);
    stageN_kernel<<<512, 512, 0, stream>>>(
        hin, hout, W0t + (s - 1) * 16384, W1t + s * 16384,
        WSt + (s - 1) * 16384, b0e + (s - 1) * 256, bse + (s - 1) * 256,
        pool + s * 256, (s < 4) ? 1 : 0, rank, (s == 4) ? 1 : 0);
    unsigned short* t = hin; hin = hout; hout = t;
  }
  gather_kernel<<<512, 256, 0, stream>>>(hin, offsets, out);
}